// Round 1
// baseline (2134.691 us; speedup 1.0000x reference)
//
#include <hip/hip_runtime.h>
#include <hip/hip_bf16.h>

// ---------------------------------------------------------------------------
// Star-Transformer-ish 2-layer forward. Layout: activations row-major
// (row = s*17+v or s, channel contiguous, C=256). All einsums become
// X(MxK) @ W(NxK)^T which matches the weights' (out, in) row-major layout.
// Round 0: fp32 everywhere, 64x64x16-tile SGEMM. MFMA-bf16 is the next step.
// ---------------------------------------------------------------------------

namespace {
constexpr int kBT = 1024;    // B*T
constexpr int kC = 256;
constexpr int kV = 17;
constexpr int kT = 256;
constexpr int kDIN = 1024;
constexpr int kRows = kBT * kV;                 // 17408
constexpr float kInvSqrtDk = 0.17677669529663687f;
constexpr size_t SZ_BIG = (size_t)kRows * kC;   // 4,456,448 floats
constexpr size_t SZ_SM = (size_t)kBT * kC;      // 262,144 floats
}  // namespace

// neighbor table (0-indexed, prefix-valid)
__constant__ int c_nbi[17][5] = {
    {0, 1, 2, 5, 6},   {0, 1, 3, 0, 0},   {0, 2, 4, 0, 0},  {1, 3, 0, 0, 0},
    {2, 4, 0, 0, 0},   {0, 5, 7, 11, 0},  {0, 6, 8, 12, 0}, {5, 7, 9, 0, 0},
    {6, 8, 12, 0, 0},  {7, 9, 0, 0, 0},   {8, 10, 0, 0, 0}, {8, 11, 13, 0, 0},
    {10, 12, 14, 0, 0},{11, 13, 15, 0, 0},{12, 14, 16, 0, 0},
    {13, 15, 0, 0, 0}, {14, 16, 0, 0, 0}};
__constant__ int c_ncnt[17] = {5, 3, 3, 2, 2, 4, 4, 3, 3, 2, 2, 3, 3, 3, 3, 2, 2};

// data (B,C,V,T) -> embs/nodes rows ((b*T+t)*V+v, c). LDS 32x32 transpose tile.
__global__ __launch_bounds__(256) void k_xform_in(const float* __restrict__ data,
                                                  float* __restrict__ embs,
                                                  float* __restrict__ nodes) {
  __shared__ float tile[32][33];
  int ct = blockIdx.x * 32, tt = blockIdx.y * 32;
  int bv = blockIdx.z;
  int b = bv / kV, v = bv - b * kV;
  int tx = threadIdx.x & 31, ty = threadIdx.x >> 5;
  for (int i = ty; i < 32; i += 8)
    tile[i][tx] = data[(((size_t)b * kC + ct + i) * kV + v) * kT + tt + tx];
  __syncthreads();
  for (int i = ty; i < 32; i += 8) {
    size_t s = (size_t)b * kT + tt + i;
    size_t idx = (s * kV + v) * kC + ct + tx;
    float val = tile[tx][i];
    embs[idx] = val;
    nodes[idx] = val;
  }
}

// nodes rows -> out (B,C,V,T)
__global__ __launch_bounds__(256) void k_xform_out(const float* __restrict__ nodes,
                                                   float* __restrict__ out) {
  __shared__ float tile[32][33];
  int ct = blockIdx.x * 32, tt = blockIdx.y * 32;
  int bv = blockIdx.z;
  int b = bv / kV, v = bv - b * kV;
  int tx = threadIdx.x & 31, ty = threadIdx.x >> 5;
  for (int i = ty; i < 32; i += 8) {
    size_t s = (size_t)b * kT + tt + i;
    tile[i][tx] = nodes[(s * kV + v) * kC + ct + tx];
  }
  __syncthreads();
  for (int i = ty; i < 32; i += 8)
    out[(((size_t)b * kC + ct + i) * kV + v) * kT + tt + tx] = tile[tx][i];
}

// relay0[s,c] = mean_v embs[s,v,c]; duplicate into relay
__global__ __launch_bounds__(256) void k_relay_init(const float* __restrict__ embs,
                                                    float* __restrict__ relay0,
                                                    float* __restrict__ relay) {
  int s = blockIdx.x, c = threadIdx.x;
  float acc = 0.f;
#pragma unroll
  for (int v = 0; v < kV; ++v) acc += embs[((size_t)s * kV + v) * kC + c];
  float r = acc * (1.f / 17.f);
  relay0[(size_t)s * kC + c] = r;
  relay[(size_t)s * kC + c] = r;
}

// per-row layernorm over C=256, eps 1e-6
__global__ __launch_bounds__(256) void k_layernorm(const float* __restrict__ X,
                                                   const float* __restrict__ g,
                                                   const float* __restrict__ b,
                                                   float* __restrict__ O) {
  int r = blockIdx.x, tid = threadIdx.x;
  float x = X[(size_t)r * kC + tid];
  float s = x, q = x * x;
#pragma unroll
  for (int o = 32; o >= 1; o >>= 1) {
    s += __shfl_xor(s, o);
    q += __shfl_xor(q, o);
  }
  __shared__ float ws[4], wq[4];
  int wid = tid >> 6;
  if ((tid & 63) == 0) { ws[wid] = s; wq[wid] = q; }
  __syncthreads();
  float S = ws[0] + ws[1] + ws[2] + ws[3];
  float Q = wq[0] + wq[1] + wq[2] + wq[3];
  float m = S * (1.f / 256.f);
  float var = Q * (1.f / 256.f) - m * m;
  O[(size_t)r * kC + tid] = (x - m) * rsqrtf(var + 1e-6f) * g[tid] + b[tid];
}

// C[M,N] = A[M,K] @ W[N,K]^T + bias (+res) (optional relu). 64x64 tile, BK=16.
__global__ __launch_bounds__(256) void k_gemm(const float* __restrict__ A,
                                              const float* __restrict__ W,
                                              const float* __restrict__ bias,
                                              const float* __restrict__ res,
                                              float* __restrict__ Cout,
                                              int M, int N, int K, int relu_flag) {
  __shared__ float As[16][68];
  __shared__ float Bs[16][68];
  int tid = threadIdx.x;
  int row0 = blockIdx.x * 64, col0 = blockIdx.y * 64;
  int lr = tid >> 2, lk = (tid & 3) << 2;
  int tx = tid & 15, ty = tid >> 4;
  const float* Ap = A + (size_t)(row0 + lr) * K + lk;
  const float* Wp = W + (size_t)(col0 + lr) * K + lk;
  float acc[4][4] = {};
  for (int k0 = 0; k0 < K; k0 += 16) {
    float4 a4 = *(const float4*)(Ap + k0);
    float4 b4 = *(const float4*)(Wp + k0);
    __syncthreads();
    As[lk + 0][lr] = a4.x; As[lk + 1][lr] = a4.y;
    As[lk + 2][lr] = a4.z; As[lk + 3][lr] = a4.w;
    Bs[lk + 0][lr] = b4.x; Bs[lk + 1][lr] = b4.y;
    Bs[lk + 2][lr] = b4.z; Bs[lk + 3][lr] = b4.w;
    __syncthreads();
#pragma unroll
    for (int kk = 0; kk < 16; ++kk) {
      float4 av = *(const float4*)&As[kk][ty << 2];
      float4 bv = *(const float4*)&Bs[kk][tx << 2];
      float a[4] = {av.x, av.y, av.z, av.w};
      float b[4] = {bv.x, bv.y, bv.z, bv.w};
#pragma unroll
      for (int i = 0; i < 4; ++i)
#pragma unroll
        for (int j = 0; j < 4; ++j) acc[i][j] += a[i] * b[j];
    }
  }
  int cb = col0 + (tx << 2);
  float4 bia = *(const float4*)&bias[cb];
#pragma unroll
  for (int i = 0; i < 4; ++i) {
    size_t r = (size_t)row0 + (ty << 2) + i;
    float4 o = make_float4(acc[i][0] + bia.x, acc[i][1] + bia.y,
                           acc[i][2] + bia.z, acc[i][3] + bia.w);
    if (res) {
      float4 rr = *(const float4*)&res[r * N + cb];
      o.x += rr.x; o.y += rr.y; o.z += rr.z; o.w += rr.w;
    }
    if (relu_flag) {
      o.x = fmaxf(o.x, 0.f); o.y = fmaxf(o.y, 0.f);
      o.z = fmaxf(o.z, 0.f); o.w = fmaxf(o.w, 0.f);
    }
    *(float4*)&Cout[r * N + cb] = o;
  }
}

// satellite attention: block per (s,l); thread = channel (h=tid>>5,d=tid&31)
__global__ __launch_bounds__(256) void k_attn_sat(const float* q, const float* kx,
                                                  const float* vx, const float* ak0,
                                                  const float* av0, const float* akr,
                                                  const float* avr, float* att) {
  int rl = blockIdx.x;
  int s = rl / kV;
  int l = rl - s * kV;
  int tid = threadIdx.x;
  float qv = q[(size_t)rl * kC + tid];
  int cnt = c_ncnt[l];
  float sc[7];
#pragma unroll
  for (int w = 0; w < 5; ++w) {
    int nb = c_nbi[l][w];
    float p = qv * kx[((size_t)s * kV + nb) * kC + tid];
#pragma unroll
    for (int o = 16; o >= 1; o >>= 1) p += __shfl_xor(p, o, 32);
    sc[w] = (w < cnt) ? p * kInvSqrtDk : -1e30f;
  }
  {
    float p = qv * ak0[(size_t)rl * kC + tid];
#pragma unroll
    for (int o = 16; o >= 1; o >>= 1) p += __shfl_xor(p, o, 32);
    sc[5] = p * kInvSqrtDk;
  }
  {
    float p = qv * akr[(size_t)s * kC + tid];
#pragma unroll
    for (int o = 16; o >= 1; o >>= 1) p += __shfl_xor(p, o, 32);
    sc[6] = p * kInvSqrtDk;
  }
  float mx = sc[0];
#pragma unroll
  for (int w = 1; w < 7; ++w) mx = fmaxf(mx, sc[w]);
  float den = 0.f;
#pragma unroll
  for (int w = 0; w < 7; ++w) {
    sc[w] = expf(sc[w] - mx);
    den += sc[w];
  }
  float inv = 1.f / den;
  float acc = 0.f;
#pragma unroll
  for (int w = 0; w < 5; ++w) {
    int nb = c_nbi[l][w];
    acc += sc[w] * vx[((size_t)s * kV + nb) * kC + tid];
  }
  acc += sc[5] * av0[(size_t)rl * kC + tid];
  acc += sc[6] * avr[(size_t)s * kC + tid];
  att[(size_t)rl * kC + tid] = acc * inv;
}

// relay attention over 18 positions (relay + 17 nodes)
__global__ __launch_bounds__(256) void k_attn_relay(const float* qr, const float* krel,
                                                    const float* kn, const float* vrel,
                                                    const float* vn, float* att) {
  int s = blockIdx.x, tid = threadIdx.x;
  float qv = qr[(size_t)s * kC + tid];
  float sc[18];
  {
    float p = qv * krel[(size_t)s * kC + tid];
#pragma unroll
    for (int o = 16; o >= 1; o >>= 1) p += __shfl_xor(p, o, 32);
    sc[0] = p * kInvSqrtDk;
  }
#pragma unroll
  for (int j = 0; j < kV; ++j) {
    float p = qv * kn[((size_t)s * kV + j) * kC + tid];
#pragma unroll
    for (int o = 16; o >= 1; o >>= 1) p += __shfl_xor(p, o, 32);
    sc[j + 1] = p * kInvSqrtDk;
  }
  float mx = sc[0];
#pragma unroll
  for (int j = 1; j < 18; ++j) mx = fmaxf(mx, sc[j]);
  float den = 0.f;
#pragma unroll
  for (int j = 0; j < 18; ++j) {
    sc[j] = expf(sc[j] - mx);
    den += sc[j];
  }
  float inv = 1.f / den;
  float acc = sc[0] * vrel[(size_t)s * kC + tid];
#pragma unroll
  for (int j = 0; j < kV; ++j) acc += sc[j + 1] * vn[((size_t)s * kV + j) * kC + tid];
  att[(size_t)s * kC + tid] = acc * inv;
}

// BN stage 1: per-block partial sums per channel; z = A (+Badd) optionally saved
__global__ __launch_bounds__(256) void k_bn_partial(const float* A, const float* Badd,
                                                    float* Z, float* part, int rows,
                                                    int rpb) {
  int c = threadIdx.x, blk = blockIdx.x;
  int lo = blk * rpb;
  int hi = lo + rpb;
  if (hi > rows) hi = rows;
  float s = 0.f, sq = 0.f;
  for (int r = lo; r < hi; ++r) {
    float v = A[(size_t)r * kC + c];
    if (Badd) v += Badd[(size_t)r * kC + c];
    if (Z) Z[(size_t)r * kC + c] = v;
    s += v;
    sq += v * v;
  }
  part[(size_t)blk * kC + c] = s;
  part[(size_t)gridDim.x * kC + (size_t)blk * kC + c] = sq;
}

// BN stage 2: finalize scale/shift per channel
__global__ __launch_bounds__(256) void k_bn_finalize(const float* part, int nb,
                                                     float inv_n, const float* g,
                                                     const float* b, float eps,
                                                     float* scale, float* shift) {
  int c = threadIdx.x;
  float s = 0.f, sq = 0.f;
  for (int i = 0; i < nb; ++i) {
    s += part[(size_t)i * kC + c];
    sq += part[(size_t)nb * kC + (size_t)i * kC + c];
  }
  float m = s * inv_n;
  float var = sq * inv_n - m * m;
  float sc = g[c] * rsqrtf(var + eps);
  scale[c] = sc;
  shift[c] = b[c] - m * sc;
}

// BN stage 3: apply (optional leaky-relu 0.01)
__global__ __launch_bounds__(256) void k_bn_apply(const float* __restrict__ Z,
                                                  const float* __restrict__ scale,
                                                  const float* __restrict__ shift,
                                                  float* __restrict__ out, int leaky) {
  int c = threadIdx.x;
  size_t i = (size_t)blockIdx.x * kC + c;
  float v = Z[i] * scale[c] + shift[c];
  if (leaky) v = (v > 0.f) ? v : 0.01f * v;
  out[i] = v;
}

extern "C" void kernel_launch(void* const* d_in, const int* in_sizes, int n_in,
                              void* d_out, int out_size, void* d_ws, size_t ws_size,
                              hipStream_t stream) {
  const float* data = (const float*)d_in[0];
  const float* ln_g = (const float*)d_in[1];
  const float* ln_b = (const float*)d_in[2];
  const float* jq_w = (const float*)d_in[3];
  const float* jq_b = (const float*)d_in[4];
  const float* jk_w = (const float*)d_in[5];
  const float* jk_b = (const float*)d_in[6];
  const float* jv_w = (const float*)d_in[7];
  const float* jv_b = (const float*)d_in[8];
  const float* jbn_g = (const float*)d_in[9];
  const float* jbn_b = (const float*)d_in[10];
  const float* jf1_w = (const float*)d_in[11];
  const float* jf1_b = (const float*)d_in[12];
  const float* jf2_w = (const float*)d_in[13];
  const float* jf2_b = (const float*)d_in[14];
  const float* jfbn_g = (const float*)d_in[15];
  const float* jfbn_b = (const float*)d_in[16];
  const float* rq_w = (const float*)d_in[17];
  const float* rq_b = (const float*)d_in[18];
  const float* rk_w = (const float*)d_in[19];
  const float* rk_b = (const float*)d_in[20];
  const float* rv_w = (const float*)d_in[21];
  const float* rv_b = (const float*)d_in[22];
  const float* rbn_g = (const float*)d_in[23];
  const float* rbn_b = (const float*)d_in[24];
  const float* rf1_w = (const float*)d_in[25];
  const float* rf1_b = (const float*)d_in[26];
  const float* rf2_w = (const float*)d_in[27];
  const float* rf2_b = (const float*)d_in[28];
  const float* rfbn_g = (const float*)d_in[29];
  const float* rfbn_b = (const float*)d_in[30];
  float* out = (float*)d_out;

  // workspace arena (~176 MB of float)
  float* w = (float*)d_ws;
  float* embs = w;                   // U0
  float* nodes = embs + SZ_BIG;      // U1
  float* xn = nodes + SZ_BIG;        // U2 (also z for first BN)
  float* kxb = xn + SZ_BIG;          // U3: kx, then ret
  float* q_att = kxb + SZ_BIG;       // U4: q/att, later h[0], later k_nodes
  float* vx = q_att + SZ_BIG;        // U5: vx, h[1], v_nodes
  float* ak0 = vx + SZ_BIG;          // U6, h[2]
  float* av0 = ak0 + SZ_BIG;         // U7, h[3]
  float* y2 = av0 + SZ_BIG;          // U8
  float* h = q_att;                  // spans U4..U7 = 17408*1024
  float* sm = y2 + SZ_BIG;
  float* relay0 = sm; sm += SZ_SM;
  float* relay = sm;  sm += SZ_SM;
  float* akr = sm;    sm += SZ_SM;
  float* avr = sm;    sm += SZ_SM;
  float* qr = sm;     sm += SZ_SM;
  float* krel = sm;   sm += SZ_SM;
  float* vrel = sm;   sm += SZ_SM;
  float* attr = sm;   sm += SZ_SM;
  float* zr = sm;     sm += SZ_SM;
  float* retr = sm;   sm += SZ_SM;
  float* yr2 = sm;    sm += SZ_SM;
  float* hr = sm;     sm += (size_t)kBT * kDIN;
  float* part = sm;   sm += 2 * 136 * kC;
  float* scale = sm;  sm += kC;
  float* shift = sm;  sm += kC;

  auto gemm = [&](const float* A, const float* W, const float* bias,
                  const float* res, float* Cb, int M, int N, int K, int relu) {
    dim3 g(M / 64, N / 64);
    k_gemm<<<g, 256, 0, stream>>>(A, W, bias, res, Cb, M, N, K, relu);
  };
  auto bn = [&](const float* Aa, const float* Ba, float* Z, int rows,
                const float* g_, const float* b_, float* dst, int leaky) {
    int nb = (rows + 127) / 128;
    k_bn_partial<<<nb, 256, 0, stream>>>(Aa, Ba, Z, part, rows, 128);
    k_bn_finalize<<<1, 256, 0, stream>>>(part, nb, 1.f / rows, g_, b_, 1e-5f,
                                         scale, shift);
    const float* zread = Z ? (const float*)Z : Aa;
    k_bn_apply<<<rows, 256, 0, stream>>>(zread, scale, shift, dst, leaky);
  };

  k_xform_in<<<dim3(8, 8, 4 * kV), 256, 0, stream>>>(data, embs, nodes);
  k_relay_init<<<kBT, 256, 0, stream>>>(embs, relay0, relay);

  for (int i = 0; i < 2; ++i) {
    const size_t om = (size_t)i * kC * kC, ob = (size_t)i * kC;
    const size_t of1 = (size_t)i * kDIN * kC, ofb1 = (size_t)i * kDIN;
    // ---- satellite (sju) ----
    k_layernorm<<<kRows, 256, 0, stream>>>(nodes, ln_g + ob, ln_b + ob, xn);
    gemm(xn, jq_w + om, jq_b + ob, nullptr, q_att, kRows, kC, kC, 0);
    gemm(xn, jk_w + om, jk_b + ob, nullptr, kxb, kRows, kC, kC, 0);
    gemm(xn, jv_w + om, jv_b + ob, nullptr, vx, kRows, kC, kC, 0);
    gemm(embs, jk_w + om, jk_b + ob, nullptr, ak0, kRows, kC, kC, 0);
    gemm(embs, jv_w + om, jv_b + ob, nullptr, av0, kRows, kC, kC, 0);
    gemm(relay0, jk_w + om, jk_b + ob, nullptr, akr, kBT, kC, kC, 0);
    gemm(relay0, jv_w + om, jv_b + ob, nullptr, avr, kBT, kC, kC, 0);
    k_attn_sat<<<kRows, 256, 0, stream>>>(q_att, kxb, vx, ak0, av0, akr, avr,
                                          q_att);
    // z = xn + att (in-place into xn), BN -> ret (kxb)
    bn(xn, q_att, xn, kRows, jbn_g + ob, jbn_b + ob, kxb, 0);
    gemm(kxb, jf1_w + of1, jf1_b + ofb1, nullptr, h, kRows, kDIN, kC, 1);
    gemm(h, jf2_w + of1, jf2_b + ob, kxb, y2, kRows, kC, kDIN, 0);
    bn(y2, nullptr, nullptr, kRows, jfbn_g + ob, jfbn_b + ob, nodes, 1);
    // ---- relay (sru) ----
    gemm(relay, rq_w + om, rq_b + ob, nullptr, qr, kBT, kC, kC, 0);
    gemm(relay, rk_w + om, rk_b + ob, nullptr, krel, kBT, kC, kC, 0);
    gemm(relay, rv_w + om, rv_b + ob, nullptr, vrel, kBT, kC, kC, 0);
    gemm(nodes, rk_w + om, rk_b + ob, nullptr, q_att, kRows, kC, kC, 0);
    gemm(nodes, rv_w + om, rv_b + ob, nullptr, vx, kRows, kC, kC, 0);
    k_attn_relay<<<kBT, 256, 0, stream>>>(qr, krel, q_att, vrel, vx, attr);
    bn(relay, attr, zr, kBT, rbn_g + ob, rbn_b + ob, retr, 0);
    gemm(retr, rf1_w + of1, rf1_b + ofb1, nullptr, hr, kBT, kDIN, kC, 1);
    gemm(hr, rf2_w + of1, rf2_b + ob, retr, yr2, kBT, kC, kDIN, 0);
    bn(yr2, nullptr, nullptr, kBT, rfbn_g + ob, rfbn_b + ob, relay, 1);
  }

  k_xform_out<<<dim3(8, 8, 4 * kV), 256, 0, stream>>>(nodes, out);
  (void)in_sizes; (void)n_in; (void)out_size; (void)ws_size;
}

// Round 2
// 1268.922 us; speedup vs baseline: 1.6823x; 1.6823x over previous
//
#include <hip/hip_runtime.h>
#include <hip/hip_bf16.h>

// ---------------------------------------------------------------------------
// Star-Transformer 2-layer forward, bf16-MFMA GEMMs (fp32 accumulate/epilogue).
// Activations row-major (row, channel) C-contiguous; all GEMMs are
// C = A(MxK) @ W(NxK)^T which matches both activation and weight layouts.
// GEMM: 128x128 tile, BK=32, global_load_lds(16B), mfma_f32_16x16x32_bf16.
// Weights converted+concatenated to bf16 each call ([jq;jk;jv], [rk;rv;rq]).
// ---------------------------------------------------------------------------

using bf16 = __hip_bfloat16;
typedef __attribute__((ext_vector_type(8))) short bf16x8v;   // 8 bf16 = 4 VGPRs
typedef __attribute__((ext_vector_type(4))) float f32x4;

namespace {
constexpr int kBT = 1024;    // B*T
constexpr int kC = 256;
constexpr int kV = 17;
constexpr int kT = 256;
constexpr int kDIN = 1024;
constexpr int kRows = kBT * kV;                 // 17408
constexpr float kInvSqrtDk = 0.17677669529663687f;
constexpr size_t SZ_BIG = (size_t)kRows * kC;   // 4,456,448
constexpr size_t SZ_SM = (size_t)kBT * kC;      // 262,144
}  // namespace

__constant__ int c_nbi[17][5] = {
    {0, 1, 2, 5, 6},   {0, 1, 3, 0, 0},   {0, 2, 4, 0, 0},  {1, 3, 0, 0, 0},
    {2, 4, 0, 0, 0},   {0, 5, 7, 11, 0},  {0, 6, 8, 12, 0}, {5, 7, 9, 0, 0},
    {6, 8, 12, 0, 0},  {7, 9, 0, 0, 0},   {8, 10, 0, 0, 0}, {8, 11, 13, 0, 0},
    {10, 12, 14, 0, 0},{11, 13, 15, 0, 0},{12, 14, 16, 0, 0},
    {13, 15, 0, 0, 0}, {14, 16, 0, 0, 0}};
__constant__ int c_ncnt[17] = {5, 3, 3, 2, 2, 4, 4, 3, 3, 2, 2, 3, 3, 3, 3, 2, 2};

__device__ inline void async16(const bf16* g, bf16* l) {
  __builtin_amdgcn_global_load_lds(
      (const __attribute__((address_space(1))) void*)g,
      (__attribute__((address_space(3))) void*)l, 16, 0, 0);
}

// ---- bf16 MFMA GEMM: C[M,N] = A[M,K]@W[N,K]^T + bias (+res), opt relu ----
// flags: 1=relu, 2=write fp32 outF, 4=write bf16 outB
__global__ __launch_bounds__(256) void k_mfma_gemm(
    const bf16* __restrict__ A, const bf16* __restrict__ W,
    const float* __restrict__ bias, const float* __restrict__ res,
    float* __restrict__ outF, bf16* __restrict__ outB,
    int M, int N, int K, int flags) {
  __shared__ bf16 As[128 * 32];
  __shared__ bf16 Bs[128 * 32];
  const int tid = threadIdx.x;
  const int wave = tid >> 6;
  const int lane = tid & 63;
  const int row0 = blockIdx.x * 128;
  const int col0 = blockIdx.y * 128;

  // staging: instruction j of wave w covers 16 rows starting (j*4+w)*16;
  // lane l -> row +(l>>2), k elems (l&3)*8. LDS dest = uniform base + lane*16B.
  const int sr0 = (0 * 4 + wave) * 16;
  const int sr1 = (1 * 4 + wave) * 16;
  const int sub = lane >> 2;
  const int kcol = (lane & 3) * 8;
  const bf16* agp0 = A + (size_t)(row0 + sr0 + sub) * K + kcol;
  const bf16* agp1 = A + (size_t)(row0 + sr1 + sub) * K + kcol;
  const bf16* bgp0 = W + (size_t)(col0 + sr0 + sub) * K + kcol;
  const bf16* bgp1 = W + (size_t)(col0 + sr1 + sub) * K + kcol;
  bf16* lda0 = &As[sr0 * 32];
  bf16* lda1 = &As[sr1 * 32];
  bf16* ldb0 = &Bs[sr0 * 32];
  bf16* ldb1 = &Bs[sr1 * 32];

  const int wm = wave >> 1, wn = wave & 1;
  const int fr = lane & 15;
  const int fk = (lane >> 4) * 8;
  const bf16* ard[4];
  const bf16* brd[4];
#pragma unroll
  for (int i = 0; i < 4; ++i) {
    ard[i] = &As[(wm * 64 + i * 16 + fr) * 32 + fk];
    brd[i] = &Bs[(wn * 64 + i * 16 + fr) * 32 + fk];
  }
  f32x4 acc[4][4];
#pragma unroll
  for (int i = 0; i < 4; ++i)
#pragma unroll
    for (int j = 0; j < 4; ++j) acc[i][j] = (f32x4){0.f, 0.f, 0.f, 0.f};

  for (int k0 = 0; k0 < K; k0 += 32) {
    __syncthreads();
    async16(agp0 + k0, lda0);
    async16(agp1 + k0, lda1);
    async16(bgp0 + k0, ldb0);
    async16(bgp1 + k0, ldb1);
    __syncthreads();
    bf16x8v af[4], bfv[4];
#pragma unroll
    for (int i = 0; i < 4; ++i) af[i] = *(const bf16x8v*)ard[i];
#pragma unroll
    for (int j = 0; j < 4; ++j) bfv[j] = *(const bf16x8v*)brd[j];
#pragma unroll
    for (int i = 0; i < 4; ++i)
#pragma unroll
      for (int j = 0; j < 4; ++j)
        acc[i][j] = __builtin_amdgcn_mfma_f32_16x16x32_bf16(af[i], bfv[j],
                                                            acc[i][j], 0, 0, 0);
  }

  const int crow = row0 + wm * 64;
  const int ccol = col0 + wn * 64;
#pragma unroll
  for (int j = 0; j < 4; ++j) {
    int col = ccol + j * 16 + fr;
    float bv = bias ? bias[col] : 0.f;
#pragma unroll
    for (int i = 0; i < 4; ++i) {
      int rowb = crow + i * 16 + (lane >> 4) * 4;
#pragma unroll
      for (int r = 0; r < 4; ++r) {
        size_t row = (size_t)(rowb + r);
        float v = acc[i][j][r] + bv;
        if (res) v += res[row * N + col];
        if (flags & 1) v = fmaxf(v, 0.f);
        if (flags & 2) outF[row * N + col] = v;
        if (flags & 4) outB[row * N + col] = __float2bfloat16(v);
      }
    }
  }
}

// data (B,C,V,T) -> nodes fp32 rows + embs bf16 rows
__global__ __launch_bounds__(256) void k_xform_in(const float* __restrict__ data,
                                                  float* __restrict__ nodes,
                                                  bf16* __restrict__ embs_bf) {
  __shared__ float tile[32][33];
  int ct = blockIdx.x * 32, tt = blockIdx.y * 32;
  int bv = blockIdx.z;
  int b = bv / kV, v = bv - b * kV;
  int tx = threadIdx.x & 31, ty = threadIdx.x >> 5;
  for (int i = ty; i < 32; i += 8)
    tile[i][tx] = data[(((size_t)b * kC + ct + i) * kV + v) * kT + tt + tx];
  __syncthreads();
  for (int i = ty; i < 32; i += 8) {
    size_t s = (size_t)b * kT + tt + i;
    size_t idx = (s * kV + v) * kC + ct + tx;
    float val = tile[tx][i];
    nodes[idx] = val;
    embs_bf[idx] = __float2bfloat16(val);
  }
}

__global__ __launch_bounds__(256) void k_xform_out(const float* __restrict__ nodes,
                                                   float* __restrict__ out) {
  __shared__ float tile[32][33];
  int ct = blockIdx.x * 32, tt = blockIdx.y * 32;
  int bv = blockIdx.z;
  int b = bv / kV, v = bv - b * kV;
  int tx = threadIdx.x & 31, ty = threadIdx.x >> 5;
  for (int i = ty; i < 32; i += 8) {
    size_t s = (size_t)b * kT + tt + i;
    tile[i][tx] = nodes[(s * kV + v) * kC + ct + tx];
  }
  __syncthreads();
  for (int i = ty; i < 32; i += 8)
    out[(((size_t)b * kC + ct + i) * kV + v) * kT + tt + tx] = tile[tx][i];
}

// relay init: mean over v of nodes; write relay fp32 + relay_bf + relay0_bf
__global__ __launch_bounds__(256) void k_relay_init(const float* __restrict__ nodes,
                                                    float* __restrict__ relay,
                                                    bf16* __restrict__ relay_bf,
                                                    bf16* __restrict__ relay0_bf) {
  int s = blockIdx.x, c = threadIdx.x;
  float acc = 0.f;
#pragma unroll
  for (int v = 0; v < kV; ++v) acc += nodes[((size_t)s * kV + v) * kC + c];
  float r = acc * (1.f / 17.f);
  size_t i = (size_t)s * kC + c;
  relay[i] = r;
  bf16 rb = __float2bfloat16(r);
  relay_bf[i] = rb;
  relay0_bf[i] = rb;
}

// per-row layernorm over C=256; writes fp32 + bf16
__global__ __launch_bounds__(256) void k_layernorm(const float* __restrict__ X,
                                                   const float* __restrict__ g,
                                                   const float* __restrict__ b,
                                                   float* __restrict__ O,
                                                   bf16* __restrict__ Ob) {
  int r = blockIdx.x, tid = threadIdx.x;
  float x = X[(size_t)r * kC + tid];
  float s = x, q = x * x;
#pragma unroll
  for (int o = 32; o >= 1; o >>= 1) {
    s += __shfl_xor(s, o);
    q += __shfl_xor(q, o);
  }
  __shared__ float ws[4], wq[4];
  int wid = tid >> 6;
  if ((tid & 63) == 0) { ws[wid] = s; wq[wid] = q; }
  __syncthreads();
  float S = ws[0] + ws[1] + ws[2] + ws[3];
  float Q = wq[0] + wq[1] + wq[2] + wq[3];
  float m = S * (1.f / 256.f);
  float var = Q * (1.f / 256.f) - m * m;
  float o = (x - m) * rsqrtf(var + 1e-6f) * g[tid] + b[tid];
  O[(size_t)r * kC + tid] = o;
  Ob[(size_t)r * kC + tid] = __float2bfloat16(o);
}

// satellite attention; qkv = [q|kx|vx] stride 768; att written over q slot.
__global__ __launch_bounds__(256) void k_attn_sat(float* __restrict__ qkv,
                                                  const float* __restrict__ akav,
                                                  const float* __restrict__ akavr) {
  int rl = blockIdx.x;
  int s = rl / kV;
  int l = rl - s * kV;
  int tid = threadIdx.x;
  float qv = qkv[(size_t)rl * 768 + tid];
  int cnt = c_ncnt[l];
  float sc[7];
#pragma unroll
  for (int w = 0; w < 5; ++w) {
    int nb = c_nbi[l][w];
    float p = qv * qkv[((size_t)s * kV + nb) * 768 + 256 + tid];
#pragma unroll
    for (int o = 16; o >= 1; o >>= 1) p += __shfl_xor(p, o, 32);
    sc[w] = (w < cnt) ? p * kInvSqrtDk : -1e30f;
  }
  {
    float p = qv * akav[(size_t)rl * 512 + tid];
#pragma unroll
    for (int o = 16; o >= 1; o >>= 1) p += __shfl_xor(p, o, 32);
    sc[5] = p * kInvSqrtDk;
  }
  {
    float p = qv * akavr[(size_t)s * 512 + tid];
#pragma unroll
    for (int o = 16; o >= 1; o >>= 1) p += __shfl_xor(p, o, 32);
    sc[6] = p * kInvSqrtDk;
  }
  float mx = sc[0];
#pragma unroll
  for (int w = 1; w < 7; ++w) mx = fmaxf(mx, sc[w]);
  float den = 0.f;
#pragma unroll
  for (int w = 0; w < 7; ++w) {
    sc[w] = expf(sc[w] - mx);
    den += sc[w];
  }
  float inv = 1.f / den;
  float acc = 0.f;
#pragma unroll
  for (int w = 0; w < 5; ++w) {
    int nb = c_nbi[l][w];
    acc += sc[w] * qkv[((size_t)s * kV + nb) * 768 + 512 + tid];
  }
  acc += sc[5] * akav[(size_t)rl * 512 + 256 + tid];
  acc += sc[6] * akavr[(size_t)s * 512 + 256 + tid];
  qkv[(size_t)rl * 768 + tid] = acc * inv;  // att over q slot
}

// relay attention: rkvq = [krel|vrel|qr] 1024x768; knv = [kn|vn] 17408x512
__global__ __launch_bounds__(256) void k_attn_relay(const float* __restrict__ rkvq,
                                                    const float* __restrict__ knv,
                                                    float* __restrict__ attr) {
  int s = blockIdx.x, tid = threadIdx.x;
  float qv = rkvq[(size_t)s * 768 + 512 + tid];
  float sc[18];
  {
    float p = qv * rkvq[(size_t)s * 768 + tid];
#pragma unroll
    for (int o = 16; o >= 1; o >>= 1) p += __shfl_xor(p, o, 32);
    sc[0] = p * kInvSqrtDk;
  }
#pragma unroll
  for (int j = 0; j < kV; ++j) {
    float p = qv * knv[((size_t)s * kV + j) * 512 + tid];
#pragma unroll
    for (int o = 16; o >= 1; o >>= 1) p += __shfl_xor(p, o, 32);
    sc[j + 1] = p * kInvSqrtDk;
  }
  float mx = sc[0];
#pragma unroll
  for (int j = 1; j < 18; ++j) mx = fmaxf(mx, sc[j]);
  float den = 0.f;
#pragma unroll
  for (int j = 0; j < 18; ++j) {
    sc[j] = expf(sc[j] - mx);
    den += sc[j];
  }
  float inv = 1.f / den;
  float acc = sc[0] * rkvq[(size_t)s * 768 + 256 + tid];
#pragma unroll
  for (int j = 0; j < kV; ++j)
    acc += sc[j + 1] * knv[((size_t)s * kV + j) * 512 + 256 + tid];
  attr[(size_t)s * kC + tid] = acc * inv;
}

// BN stage 1: partial sums; optionally z = A + B saved (Z stride 256)
__global__ __launch_bounds__(256) void k_bn_partial(const float* __restrict__ A,
                                                    const float* __restrict__ B,
                                                    int ldb, float* __restrict__ Z,
                                                    float* __restrict__ part,
                                                    int rows, int rpb) {
  int c = threadIdx.x, blk = blockIdx.x;
  int lo = blk * rpb;
  int hi = lo + rpb;
  if (hi > rows) hi = rows;
  float s = 0.f, sq = 0.f;
  for (int r = lo; r < hi; ++r) {
    float v = A[(size_t)r * kC + c];
    if (B) v += B[(size_t)r * ldb + c];
    if (Z) Z[(size_t)r * kC + c] = v;
    s += v;
    sq += v * v;
  }
  part[(size_t)blk * kC + c] = s;
  part[(size_t)gridDim.x * kC + (size_t)blk * kC + c] = sq;
}

__global__ __launch_bounds__(256) void k_bn_finalize(const float* __restrict__ part,
                                                     int nb, float inv_n,
                                                     const float* __restrict__ g,
                                                     const float* __restrict__ b,
                                                     float eps,
                                                     float* __restrict__ scale,
                                                     float* __restrict__ shift) {
  int c = threadIdx.x;
  float s = 0.f, sq = 0.f;
  for (int i = 0; i < nb; ++i) {
    s += part[(size_t)i * kC + c];
    sq += part[(size_t)nb * kC + (size_t)i * kC + c];
  }
  float m = s * inv_n;
  float var = sq * inv_n - m * m;
  float sc = g[c] * rsqrtf(var + eps);
  scale[c] = sc;
  shift[c] = b[c] - m * sc;
}

// BN stage 3: apply (+opt leaky), write fp32 + opt bf16
__global__ __launch_bounds__(256) void k_bn_apply(const float* __restrict__ Z,
                                                  const float* __restrict__ scale,
                                                  const float* __restrict__ shift,
                                                  float* __restrict__ outF,
                                                  bf16* __restrict__ outB,
                                                  int leaky) {
  int c = threadIdx.x;
  size_t i = (size_t)blockIdx.x * kC + c;
  float v = Z[i] * scale[c] + shift[c];
  if (leaky) v = (v > 0.f) ? v : 0.01f * v;
  outF[i] = v;
  if (outB) outB[i] = __float2bfloat16(v);
}

// flat f32 -> bf16, n multiple of 1024
__global__ __launch_bounds__(256) void k_cvt(const float* __restrict__ s,
                                             bf16* __restrict__ d, int n) {
  int i = (blockIdx.x * 256 + threadIdx.x) * 4;
  if (i + 3 < n) {
    float4 v = *(const float4*)(s + i);
    d[i + 0] = __float2bfloat16(v.x);
    d[i + 1] = __float2bfloat16(v.y);
    d[i + 2] = __float2bfloat16(v.z);
    d[i + 3] = __float2bfloat16(v.w);
  }
}

// concat up to 3 bias vectors of 256
__global__ __launch_bounds__(256) void k_cat3(float* __restrict__ dst,
                                              const float* __restrict__ a,
                                              const float* __restrict__ b,
                                              const float* __restrict__ c) {
  int tid = threadIdx.x;
  dst[tid] = a[tid];
  dst[256 + tid] = b[tid];
  if (c) dst[512 + tid] = c[tid];
}

extern "C" void kernel_launch(void* const* d_in, const int* in_sizes, int n_in,
                              void* d_out, int out_size, void* d_ws, size_t ws_size,
                              hipStream_t stream) {
  const float* data = (const float*)d_in[0];
  const float* ln_g = (const float*)d_in[1];
  const float* ln_b = (const float*)d_in[2];
  const float* jq_w = (const float*)d_in[3];
  const float* jq_b = (const float*)d_in[4];
  const float* jk_w = (const float*)d_in[5];
  const float* jk_b = (const float*)d_in[6];
  const float* jv_w = (const float*)d_in[7];
  const float* jv_b = (const float*)d_in[8];
  const float* jbn_g = (const float*)d_in[9];
  const float* jbn_b = (const float*)d_in[10];
  const float* jf1_w = (const float*)d_in[11];
  const float* jf1_b = (const float*)d_in[12];
  const float* jf2_w = (const float*)d_in[13];
  const float* jf2_b = (const float*)d_in[14];
  const float* jfbn_g = (const float*)d_in[15];
  const float* jfbn_b = (const float*)d_in[16];
  const float* rq_w = (const float*)d_in[17];
  const float* rq_b = (const float*)d_in[18];
  const float* rk_w = (const float*)d_in[19];
  const float* rk_b = (const float*)d_in[20];
  const float* rv_w = (const float*)d_in[21];
  const float* rv_b = (const float*)d_in[22];
  const float* rbn_g = (const float*)d_in[23];
  const float* rbn_b = (const float*)d_in[24];
  const float* rf1_w = (const float*)d_in[25];
  const float* rf1_b = (const float*)d_in[26];
  const float* rf2_w = (const float*)d_in[27];
  const float* rf2_b = (const float*)d_in[28];
  const float* rfbn_g = (const float*)d_in[29];
  const float* rfbn_b = (const float*)d_in[30];
  float* out = (float*)d_out;

  // ---- arena ----
  float* f = (float*)d_ws;
  float* nodes = f;               f += SZ_BIG;   // also 'ret' between BN1/BN2
  float* xn = f;                  f += SZ_BIG;
  float* qkv = f;                 f += 3 * SZ_BIG;  // q|kx|vx; att over q slot;
                                                    // later y2 (slot0), knv (512-wide)
  float* akav = f;                f += 2 * SZ_BIG;  // ak0|av0; later h_bf alias
  float* relay = f;               f += SZ_SM;
  float* retr = f;                f += SZ_SM;
  float* yr2 = f;                 f += SZ_SM;
  float* rkvq_s = f;              f += 3 * SZ_SM;   // krel|vrel|qr
  float* akavr = f;               f += 2 * SZ_SM;   // also hr_bf alias
  float* attr = f;                f += SZ_SM;
  float* part = f;                f += 2 * 136 * kC;
  float* scale = f;               f += kC;
  float* shift = f;               f += kC;
  float* cb_jqkv = f;             f += 2 * 768;
  float* cb_rkvq = f;             f += 2 * 768;
  bf16* bfa = (bf16*)f;
  bf16* embs_bf = bfa;            bfa += SZ_BIG;
  bf16* act_bf = bfa;             bfa += SZ_BIG;   // xn_bf -> ret_bf -> nodes_bf
  bf16* relay_bf = bfa;           bfa += SZ_SM;
  bf16* relay0_bf = bfa;          bfa += SZ_SM;
  bf16* retr_bf = bfa;            bfa += SZ_SM;
  bf16* Wjqkv = bfa;              bfa += 2 * 768 * 256;
  bf16* Wjf1 = bfa;               bfa += 2 * 1024 * 256;
  bf16* Wjf2 = bfa;               bfa += 2 * 256 * 1024;
  bf16* Wrkvq = bfa;              bfa += 2 * 768 * 256;
  bf16* Wrf1 = bfa;               bfa += 2 * 1024 * 256;
  bf16* Wrf2 = bfa;               bfa += 2 * 256 * 1024;
  float* y2 = qkv;                       // 17408x256 contiguous
  float* knv = qkv;                      // 17408x512 contiguous
  bf16* h_bf = (bf16*)akav;              // 17408x1024 bf16 == 2*SZ_BIG fp32
  bf16* hr_bf = (bf16*)akavr;            // 1024x1024 bf16 == 2*SZ_SM fp32

  auto gemm = [&](const bf16* A, const bf16* W, const float* bias,
                  const float* res, float* oF, bf16* oB, int M, int N, int K,
                  int flags) {
    dim3 g(M / 128, N / 128);
    k_mfma_gemm<<<g, 256, 0, stream>>>(A, W, bias, res, oF, oB, M, N, K, flags);
  };
  auto cvt = [&](const float* s, bf16* d, int n) {
    k_cvt<<<n / 1024, 256, 0, stream>>>(s, d, n);
  };

  // ---- weight conversion / concatenation ----
  for (int i = 0; i < 2; ++i) {
    const size_t om = (size_t)i * kC * kC;
    const size_t of = (size_t)i * kDIN * kC;
    cvt(jq_w + om, Wjqkv + (size_t)i * 768 * 256 + 0 * 65536, 65536);
    cvt(jk_w + om, Wjqkv + (size_t)i * 768 * 256 + 1 * 65536, 65536);
    cvt(jv_w + om, Wjqkv + (size_t)i * 768 * 256 + 2 * 65536, 65536);
    cvt(rk_w + om, Wrkvq + (size_t)i * 768 * 256 + 0 * 65536, 65536);
    cvt(rv_w + om, Wrkvq + (size_t)i * 768 * 256 + 1 * 65536, 65536);
    cvt(rq_w + om, Wrkvq + (size_t)i * 768 * 256 + 2 * 65536, 65536);
    k_cat3<<<1, 256, 0, stream>>>(cb_jqkv + i * 768, jq_b + (size_t)i * kC,
                                  jk_b + (size_t)i * kC, jv_b + (size_t)i * kC);
    k_cat3<<<1, 256, 0, stream>>>(cb_rkvq + i * 768, rk_b + (size_t)i * kC,
                                  rv_b + (size_t)i * kC, rq_b + (size_t)i * kC);
    (void)of;
  }
  cvt(jf1_w, Wjf1, 2 * 1024 * 256);
  cvt(jf2_w, Wjf2, 2 * 256 * 1024);
  cvt(rf1_w, Wrf1, 2 * 1024 * 256);
  cvt(rf2_w, Wrf2, 2 * 256 * 1024);

  k_xform_in<<<dim3(8, 8, 4 * kV), 256, 0, stream>>>(data, nodes, embs_bf);
  k_relay_init<<<kBT, 256, 0, stream>>>(nodes, relay, relay_bf, relay0_bf);

  auto bn = [&](const float* A, const float* B, int ldb, float* Z, int rows,
                const float* g_, const float* b_, float* dstF, bf16* dstB,
                int leaky) {
    int nb = (rows + 127) / 128;
    k_bn_partial<<<nb, 256, 0, stream>>>(A, B, ldb, Z, part, rows, 128);
    k_bn_finalize<<<1, 256, 0, stream>>>(part, nb, 1.f / rows, g_, b_, 1e-5f,
                                         scale, shift);
    const float* zr = Z ? (const float*)Z : A;
    k_bn_apply<<<rows, 256, 0, stream>>>(zr, scale, shift, dstF, dstB, leaky);
  };

  for (int i = 0; i < 2; ++i) {
    const size_t ob = (size_t)i * kC, ofb1 = (size_t)i * kDIN;
    const bf16* Wj = Wjqkv + (size_t)i * 768 * 256;
    const bf16* Wr = Wrkvq + (size_t)i * 768 * 256;
    const bf16* Wf1 = Wjf1 + (size_t)i * 1024 * 256;
    const bf16* Wf2 = Wjf2 + (size_t)i * 256 * 1024;
    const bf16* Wg1 = Wrf1 + (size_t)i * 1024 * 256;
    const bf16* Wg2 = Wrf2 + (size_t)i * 256 * 1024;
    const float* cbj = cb_jqkv + i * 768;
    const float* cbr = cb_rkvq + i * 768;

    // ---- satellite ----
    k_layernorm<<<kRows, 256, 0, stream>>>(nodes, ln_g + ob, ln_b + ob, xn, act_bf);
    gemm(act_bf, Wj, cbj, nullptr, qkv, nullptr, kRows, 768, 256, 2);
    gemm(embs_bf, Wj + 256 * 256, cbj + 256, nullptr, akav, nullptr, kRows, 512,
         256, 2);
    gemm(relay0_bf, Wj + 256 * 256, cbj + 256, nullptr, akavr, nullptr, kBT, 512,
         256, 2);
    k_attn_sat<<<kRows, 256, 0, stream>>>(qkv, akav, akavr);
    // z = xn + att(q-slot of qkv, ld 768) -> BN -> ret(nodes buf) + ret_bf
    bn(xn, qkv, 768, xn, kRows, jbn_g + ob, jbn_b + ob, nodes, act_bf, 0);
    gemm(act_bf, Wf1, jf1_b + ofb1, nullptr, nullptr, h_bf, kRows, 1024, 256,
         4 | 1);
    gemm(h_bf, Wf2, jf2_b + ob, nodes, y2, nullptr, kRows, 256, 1024, 2);
    bn(y2, nullptr, 0, nullptr, kRows, jfbn_g + ob, jfbn_b + ob, nodes, act_bf, 1);

    // ---- relay ----
    gemm(relay_bf, Wr, cbr, nullptr, rkvq_s, nullptr, kBT, 768, 256, 2);
    gemm(act_bf, Wr, cbr, nullptr, knv, nullptr, kRows, 512, 256, 2);
    k_attn_relay<<<kBT, 256, 0, stream>>>(rkvq_s, knv, attr);
    bn(relay, attr, 256, relay, kBT, rbn_g + ob, rbn_b + ob, retr, retr_bf, 0);
    gemm(retr_bf, Wg1, rf1_b + ofb1, nullptr, nullptr, hr_bf, kBT, 1024, 256,
         4 | 1);
    gemm(hr_bf, Wg2, rf2_b + ob, retr, yr2, nullptr, kBT, 256, 1024, 2);
    bn(yr2, nullptr, 0, nullptr, kBT, rfbn_g + ob, rfbn_b + ob, relay, relay_bf,
       1);
  }

  k_xform_out<<<dim3(8, 8, 4 * kV), 256, 0, stream>>>(nodes, out);
  (void)in_sizes; (void)n_in; (void)out_size; (void)ws_size;
}